// Round 25
// baseline (199.263 us; speedup 1.0000x reference)
//
#include <hip/hip_runtime.h>
#include <hip/hip_cooperative_groups.h>

// Problem: B=4, C=256, C4=64, N=4096, f32 in/out.
//   Q = Wqk@x; V = Wv@x + b; E = Q^T Q / 8; A = softmax_rows(E); out = V @ A
// Fused: out[c,m] = sum_n V[c,n] * exp2(dot_nm - 12) * Zinv[n],
//        Zinv[n] = 4096 / sum_m exp2(dot_nm);  dot = log2e*E (Qt pre-scaled).
// R14: FRAG-BLOCKED Qt (contiguous 1-KB wave tile loads). R20: V blocked f16,
// Zinv folded into av bt. R23/R24: z writes Zinv directly, 64-n full-m blocks.
// R25: ONE COOPERATIVE KERNEL (512 blocks x 512 thr, 2 grid.sync()) replaces
// the 3 dispatches — removes inter-dispatch gaps. Phase bodies = R24 kernels
// re-partitioned. Fallback to the 3 R24 launches if coop launch fails.

#define CC 256
#define C4C 64
#define NBATCH 4
#define NN 4096
#define QSCALE 0.42466089f   // sqrt(log2(e)/8)
#define SHIFT2 12.0f

namespace cg = cooperative_groups;

typedef _Float16 f16;
typedef _Float16 half2v __attribute__((ext_vector_type(2)));
typedef _Float16 half4 __attribute__((ext_vector_type(4)));
typedef _Float16 half8 __attribute__((ext_vector_type(8)));
typedef __fp16 fp16x2 __attribute__((ext_vector_type(2)));
typedef float floatx4 __attribute__((ext_vector_type(4)));

static __device__ __forceinline__ half2v pkrtz(float a, float b) {
  fp16x2 r = __builtin_amdgcn_cvt_pkrtz(a, b);
  return __builtin_bit_cast(half2v, r);
}

// Load one 16-n tile's MFMA frag pair: lane l gets {row=l&15, k=8*(l>>4)+j}
#define LOADQ(T, A0, A1)                                                   \
  { const f16* p_ = Qb + (size_t)(T) * 1024 + l * 8;                       \
    A0 = *(const half8*)(p_); A1 = *(const half8*)(p_ + 512); }

#define XT_PITCH 264

// ================= FUSED cooperative kernel ==================================
// grid 512 x block 512 (8 waves). Phase1 qv: block = 32 n x 128 oc (wave =
// 16 oc, Q if w<4 else V). Phase2 z: blocks 0..255 = R24 z (64 n x full m).
// Phase3 av: R24 av. 2 grid syncs.
__global__ __launch_bounds__(512, 4) void fused_kernel(
    const float* __restrict__ x, const float* __restrict__ Wqk,
    const float* __restrict__ Wv, const float* __restrict__ bv,
    f16* __restrict__ Qtb, f16* __restrict__ V4,
    float* __restrict__ Zinv, float* __restrict__ Out)
{
  __shared__ __align__(16) f16 xt[32][XT_PITCH];
  __shared__ float zl[8][64];
  __shared__ float red[8][2][16][17];

  const int bx = blockIdx.x;
  const int xcd = bx & 7, slot = bx >> 3;          // slot 0..63
  const int b = xcd >> 1;                          // 2 XCDs per batch
  const int tid = threadIdx.x;
  const int w = tid >> 6, l = tid & 63, lr = l & 15, lg = l >> 4;

  // ---------------- phase 1: QV ----------------
  {
    const int wu = ((xcd & 1) << 6) | slot;        // 0..127
    const int n0 = wu * 32;
    {  // stage x -> xt transposed f16 (512 thr: 4c x 4n register transpose)
      const int nq = tid & 7;
      const int cb = tid >> 3;                     // 0..63
      const int c = cb * 4;
      const float* xp = x + (size_t)b * CC * NN + n0 + nq * 4;
      float4 r[4];
#pragma unroll
      for (int j = 0; j < 4; ++j)
        r[j] = *(const float4*)(xp + (size_t)(c + j) * NN);
#pragma unroll
      for (int s = 0; s < 4; ++s) {
        half4 h;
#pragma unroll
        for (int j = 0; j < 4; ++j) h[j] = (f16)(((const float*)&r[j])[s]);
        *(half4*)(&xt[nq * 4 + s][c]) = h;
      }
    }
    const float* Wsrc = (w < 4) ? Wqk : Wv;
    const int oc16 = (w & 3) * 16;
    half8 af[8];
    {
      const float* wp = Wsrc + (size_t)(oc16 + lr) * CC + 8 * lg;
#pragma unroll
      for (int kk = 0; kk < 8; ++kk) {
        float4 wa = *(const float4*)(wp + kk * 32);
        float4 wb = *(const float4*)(wp + kk * 32 + 4);
        half8 h;
        h[0] = (f16)wa.x; h[1] = (f16)wa.y; h[2] = (f16)wa.z; h[3] = (f16)wa.w;
        h[4] = (f16)wb.x; h[5] = (f16)wb.y; h[6] = (f16)wb.z; h[7] = (f16)wb.w;
        af[kk] = h;
      }
    }
    __syncthreads();
    floatx4 acc[2] = {{0.f,0.f,0.f,0.f},{0.f,0.f,0.f,0.f}};
#pragma unroll
    for (int nt = 0; nt < 2; ++nt)
#pragma unroll
      for (int kk = 0; kk < 8; ++kk) {
        half8 bf = *(const half8*)(&xt[nt * 16 + lr][kk * 32 + 8 * lg]);
        acc[nt] = __builtin_amdgcn_mfma_f32_16x16x32_f16(af[kk], bf, acc[nt], 0, 0, 0);
      }
    if (w < 4) {
      // Q blocked write: oc = w*16 + 4lg + i -> blk=w>>1, kg=2(w&1)+(lg>>1)
#pragma unroll
      for (int nt = 0; nt < 2; ++nt) {
        int T = (n0 >> 4) + nt;
        int kg = 2 * (w & 1) + (lg >> 1);
        union { f16 h[4]; unsigned long long u; } q4;
#pragma unroll
        for (int i = 0; i < 4; ++i) q4.h[i] = (f16)(acc[nt][i] * QSCALE);
        *(unsigned long long*)(Qtb + (size_t)(b * 256 + T) * 1024 + (w >> 1) * 512
                               + (kg * 16 + lr) * 8 + (lg & 1) * 4) = q4.u;
      }
    } else {
#pragma unroll
      for (int nt = 0; nt < 2; ++nt) {
        int T = (n0 >> 4) + nt;
        int oc = oc16 + 4 * lg;
#pragma unroll
        for (int i = 0; i < 4; ++i)
          V4[(size_t)(b * 256 + T) * 1024 + (oc + i) * 16 + lr] =
              (f16)(acc[nt][i] + bv[oc + i]);
      }
    }
  }
  cg::this_grid().sync();

  // ---------------- phase 2: Z (blocks 0..255 = R24 z) ----------------
  if (bx < 256) {
    const int xcd2 = bx & 7, slot2 = bx >> 3;      // slot2 0..31
    const int b2 = xcd2 >> 1;
    const int wu2 = ((xcd2 & 1) << 5) | slot2;     // 0..63
    const int n0t = wu2 * 4;                       // 64-n group
    const f16* Qb = Qtb + (size_t)b2 * 256 * 1024;

    half8 a[4][2];
#pragma unroll
    for (int t = 0; t < 4; ++t) LOADQ(n0t + t, a[t][0], a[t][1]);

    const int tstr = w * 32;
    float rs[4][4];
#pragma unroll
    for (int t = 0; t < 4; ++t)
#pragma unroll
      for (int i = 0; i < 4; ++i) rs[t][i] = 0.f;

#pragma unroll 1
    for (int ch = 0; ch < 4; ++ch) {
      half8 bb[8][2];
#pragma unroll
      for (int mt = 0; mt < 8; ++mt) {
        const f16* p_ = Qb + (size_t)(tstr + ch * 8 + mt) * 1024 + l * 8;
        bb[mt][0] = *(const half8*)(p_);
        bb[mt][1] = *(const half8*)(p_ + 512);
      }
#pragma unroll
      for (int mt = 0; mt < 8; ++mt) {
        floatx4 d[4];
#pragma unroll
        for (int t = 0; t < 4; ++t) {
          d[t] = (floatx4){0.f, 0.f, 0.f, 0.f};
          d[t] = __builtin_amdgcn_mfma_f32_16x16x32_f16(a[t][0], bb[mt][0], d[t], 0, 0, 0);
          d[t] = __builtin_amdgcn_mfma_f32_16x16x32_f16(a[t][1], bb[mt][1], d[t], 0, 0, 0);
        }
#pragma unroll
        for (int t = 0; t < 4; ++t)
#pragma unroll
          for (int i = 0; i < 4; ++i)
            rs[t][i] += __builtin_amdgcn_exp2f(d[t][i]);
      }
    }

#pragma unroll
    for (int t = 0; t < 4; ++t)
#pragma unroll
      for (int i = 0; i < 4; ++i) {
        float v = rs[t][i];
        v += __shfl_xor(v, 1); v += __shfl_xor(v, 2);
        v += __shfl_xor(v, 4); v += __shfl_xor(v, 8);
        rs[t][i] = v;
      }
    if (lr == 0) {
#pragma unroll
      for (int t = 0; t < 4; ++t)
#pragma unroll
        for (int i = 0; i < 4; ++i)
          zl[w][16 * t + 4 * lg + i] = rs[t][i];
    }
    __syncthreads();
    if (tid < 64) {   // fixed-order 8-wave sum -> complete Z -> Zinv
      float s = 0.f;
#pragma unroll
      for (int ww = 0; ww < 8; ++ww) s += zl[ww][tid];
      Zinv[b2 * NN + n0t * 16 + tid] = 4096.0f / s;
    }
  }
  cg::this_grid().sync();

  // ---------------- phase 3: AV (R24 av, all 512 blocks) ----------------
  {
    const int m0 = (((xcd & 1) << 6) | slot) * 32; // 128 m-tiles per batch
    const f16* Qb = Qtb + (size_t)b * 256 * 1024;
    const f16* Vb = V4 + (size_t)b * 256 * 1024;
    const float* Zb = Zinv + b * NN;

    half8 bq[2][2];
    LOADQ((m0 >> 4), bq[0][0], bq[0][1]);
    LOADQ((m0 >> 4) + 1, bq[1][0], bq[1][1]);

    floatx4 o[4][2];
#pragma unroll
    for (int cs = 0; cs < 4; ++cs)
#pragma unroll
      for (int t = 0; t < 2; ++t) o[cs][t] = (floatx4){0.f, 0.f, 0.f, 0.f};

#pragma unroll 2
    for (int it = 0; it < 32; ++it) {
      const int T = it * 8 + w;
      half8 a0, a1;
      LOADQ(T, a0, a1);
      half4 va[4];
      {
        const f16* up_ = Vb + (size_t)T * 1024 + 4 * lg;
#pragma unroll
        for (int cs = 0; cs < 4; ++cs)
          va[cs] = *(const half4*)(up_ + (16 * cs + lr) * 16);
      }
      const float4 zi = *(const float4*)(Zb + T * 16 + 4 * lg);

      floatx4 dA = {-SHIFT2, -SHIFT2, -SHIFT2, -SHIFT2};
      floatx4 dB = {-SHIFT2, -SHIFT2, -SHIFT2, -SHIFT2};
      dA = __builtin_amdgcn_mfma_f32_16x16x32_f16(a0, bq[0][0], dA, 0, 0, 0);
      dB = __builtin_amdgcn_mfma_f32_16x16x32_f16(a0, bq[1][0], dB, 0, 0, 0);
      dA = __builtin_amdgcn_mfma_f32_16x16x32_f16(a1, bq[0][1], dA, 0, 0, 0);
      dB = __builtin_amdgcn_mfma_f32_16x16x32_f16(a1, bq[1][1], dB, 0, 0, 0);

      half2v p0a = pkrtz(__builtin_amdgcn_exp2f(dA[0]) * zi.x,
                         __builtin_amdgcn_exp2f(dA[1]) * zi.y);
      half2v p0b = pkrtz(__builtin_amdgcn_exp2f(dA[2]) * zi.z,
                         __builtin_amdgcn_exp2f(dA[3]) * zi.w);
      half2v p1a = pkrtz(__builtin_amdgcn_exp2f(dB[0]) * zi.x,
                         __builtin_amdgcn_exp2f(dB[1]) * zi.y);
      half2v p1b = pkrtz(__builtin_amdgcn_exp2f(dB[2]) * zi.z,
                         __builtin_amdgcn_exp2f(dB[3]) * zi.w);
      half4 bt0 = {p0a[0], p0a[1], p0b[0], p0b[1]};
      half4 bt1 = {p1a[0], p1a[1], p1b[0], p1b[1]};
#pragma unroll
      for (int cs = 0; cs < 4; ++cs) {
        o[cs][0] = __builtin_amdgcn_mfma_f32_16x16x16f16(va[cs], bt0, o[cs][0], 0, 0, 0);
        o[cs][1] = __builtin_amdgcn_mfma_f32_16x16x16f16(va[cs], bt1, o[cs][1], 0, 0, 0);
      }
    }

#pragma unroll 1
    for (int cs = 0; cs < 4; ++cs) {
      __syncthreads();
#pragma unroll
      for (int t = 0; t < 2; ++t)
#pragma unroll
        for (int i = 0; i < 4; ++i)
          red[w][t][4 * lg + i][lr] = o[cs][t][i];
      __syncthreads();
      const int t = tid >> 8;
      const int r = (tid >> 4) & 15;
      const int col = tid & 15;
      float ssum = 0.f;
#pragma unroll
      for (int ww = 0; ww < 8; ++ww) ssum += red[ww][t][r][col];
      Out[((size_t)b * C4C + cs * 16 + r) * NN + m0 + t * 16 + col] = ssum;
    }
  }
}

// ================= R24 fallback kernels (unchanged) ==========================
__global__ __launch_bounds__(256) void qv_kernel(
    const float* __restrict__ x, const float* __restrict__ Wqk,
    const float* __restrict__ Wv, const float* __restrict__ bv,
    f16* __restrict__ Qtb, f16* __restrict__ V4)
{
  __shared__ __align__(16) f16 xt[32][XT_PITCH];
  const int b = blockIdx.y;
  const int n0 = blockIdx.x * 32;
  const int tid = threadIdx.x;

  {
    const int nq = tid & 7;
    const int cb = tid >> 3;
    const int c = cb * 8;
    const float* xp = x + (size_t)b * CC * NN + n0 + nq * 4;
    float4 r[8];
#pragma unroll
    for (int j = 0; j < 8; ++j)
      r[j] = *(const float4*)(xp + (size_t)(c + j) * NN);
#pragma unroll
    for (int s = 0; s < 4; ++s) {
      half8 h;
#pragma unroll
      for (int j = 0; j < 8; ++j) h[j] = (f16)(((const float*)&r[j])[s]);
      *(half8*)(&xt[nq * 4 + s][c]) = h;
    }
  }

  const int w = tid >> 6, l = tid & 63, lr = l & 15, lg = l >> 4;
  const float* Wsrc = (w < 2) ? Wqk : Wv;
  const int ocb = (w & 1) * 32;
  half8 af[2][8];
#pragma unroll
  for (int t = 0; t < 2; ++t) {
    const float* wp = Wsrc + (size_t)(ocb + t * 16 + lr) * CC + 8 * lg;
#pragma unroll
    for (int kk = 0; kk < 8; ++kk) {
      float4 wa = *(const float4*)(wp + kk * 32);
      float4 wb = *(const float4*)(wp + kk * 32 + 4);
      half8 h;
      h[0] = (f16)wa.x; h[1] = (f16)wa.y; h[2] = (f16)wa.z; h[3] = (f16)wa.w;
      h[4] = (f16)wb.x; h[5] = (f16)wb.y; h[6] = (f16)wb.z; h[7] = (f16)wb.w;
      af[t][kk] = h;
    }
  }

  __syncthreads();

  floatx4 acc[2][2] = {{{0.f,0.f,0.f,0.f},{0.f,0.f,0.f,0.f}},
                       {{0.f,0.f,0.f,0.f},{0.f,0.f,0.f,0.f}}};
#pragma unroll
  for (int nt = 0; nt < 2; ++nt) {
#pragma unroll
    for (int kk = 0; kk < 8; ++kk) {
      half8 bf = *(const half8*)(&xt[nt * 16 + lr][kk * 32 + 8 * lg]);
      acc[0][nt] = __builtin_amdgcn_mfma_f32_16x16x32_f16(af[0][kk], bf, acc[0][nt], 0, 0, 0);
      acc[1][nt] = __builtin_amdgcn_mfma_f32_16x16x32_f16(af[1][kk], bf, acc[1][nt], 0, 0, 0);
    }
  }

  if (w < 2) {
#pragma unroll
    for (int t = 0; t < 2; ++t)
#pragma unroll
      for (int nt = 0; nt < 2; ++nt) {
        int T = (n0 >> 4) + nt;
        int kg = 2 * t + (lg >> 1);
        union { f16 h[4]; unsigned long long u; } q4;
#pragma unroll
        for (int i = 0; i < 4; ++i) q4.h[i] = (f16)(acc[t][nt][i] * QSCALE);
        *(unsigned long long*)(Qtb + (size_t)(b * 256 + T) * 1024 + w * 512
                               + (kg * 16 + lr) * 8 + (lg & 1) * 4) = q4.u;
      }
  } else {
#pragma unroll
    for (int t = 0; t < 2; ++t)
#pragma unroll
      for (int nt = 0; nt < 2; ++nt) {
        int T = (n0 >> 4) + nt;
        int oc = (w - 2) * 32 + t * 16 + 4 * lg;
#pragma unroll
        for (int i = 0; i < 4; ++i)
          V4[(size_t)(b * 256 + T) * 1024 + (oc + i) * 16 + lr] =
              (f16)(acc[t][nt][i] + bv[oc + i]);
      }
  }
}

__global__ __launch_bounds__(512) void z_kernel(
    const f16* __restrict__ Qtb, float* __restrict__ Zinv)
{
  __shared__ float zl[8][64];
  const int bx = blockIdx.x;
  const int xcd = bx & 7, slot = bx >> 3;
  const int b = xcd >> 1;
  const int wu = ((xcd & 1) << 5) | slot;
  const int n0t = wu * 4;
  const int tid = threadIdx.x;
  const int w = tid >> 6, l = tid & 63, lr = l & 15, lg = l >> 4;
  const f16* Qb = Qtb + (size_t)b * 256 * 1024;

  half8 a[4][2];
#pragma unroll
  for (int t = 0; t < 4; ++t) LOADQ(n0t + t, a[t][0], a[t][1]);

  const int tstr = w * 32;
  float rs[4][4];
#pragma unroll
  for (int t = 0; t < 4; ++t)
#pragma unroll
    for (int i = 0; i < 4; ++i) rs[t][i] = 0.f;

#pragma unroll 1
  for (int ch = 0; ch < 4; ++ch) {
    half8 bb[8][2];
#pragma unroll
    for (int mt = 0; mt < 8; ++mt) {
      const f16* p_ = Qb + (size_t)(tstr + ch * 8 + mt) * 1024 + l * 8;
      bb[mt][0] = *(const half8*)(p_);
      bb[mt][1] = *(const half8*)(p_ + 512);
    }
#pragma unroll
    for (int mt = 0; mt < 8; ++mt) {
      floatx4 d[4];
#pragma unroll
      for (int t = 0; t < 4; ++t) {
        d[t] = (floatx4){0.f, 0.f, 0.f, 0.f};
        d[t] = __builtin_amdgcn_mfma_f32_16x16x32_f16(a[t][0], bb[mt][0], d[t], 0, 0, 0);
        d[t] = __builtin_amdgcn_mfma_f32_16x16x32_f16(a[t][1], bb[mt][1], d[t], 0, 0, 0);
      }
#pragma unroll
      for (int t = 0; t < 4; ++t)
#pragma unroll
        for (int i = 0; i < 4; ++i)
          rs[t][i] += __builtin_amdgcn_exp2f(d[t][i]);
    }
  }

#pragma unroll
  for (int t = 0; t < 4; ++t)
#pragma unroll
    for (int i = 0; i < 4; ++i) {
      float v = rs[t][i];
      v += __shfl_xor(v, 1); v += __shfl_xor(v, 2);
      v += __shfl_xor(v, 4); v += __shfl_xor(v, 8);
      rs[t][i] = v;
    }
  if (lr == 0) {
#pragma unroll
    for (int t = 0; t < 4; ++t)
#pragma unroll
      for (int i = 0; i < 4; ++i)
        zl[w][16 * t + 4 * lg + i] = rs[t][i];
  }
  __syncthreads();
  if (tid < 64) {
    float s = 0.f;
#pragma unroll
    for (int ww = 0; ww < 8; ++ww) s += zl[ww][tid];
    Zinv[b * NN + n0t * 16 + tid] = 4096.0f / s;
  }
}

#define LOADV(NB, UA)                                                      \
  { const f16* up_ = Vb + (size_t)(NB) * 1024 + 4 * lg;                    \
    _Pragma("unroll")                                                      \
    for (int cs = 0; cs < 4; ++cs)                                         \
      UA[cs] = *(const half4*)(up_ + (16 * cs + lr) * 16); }

__global__ __launch_bounds__(512, 4) void av_kernel(
    const f16* __restrict__ Qtb, const f16* __restrict__ V4,
    const float* __restrict__ Zinv, float* __restrict__ Out)
{
  __shared__ float red[8][2][16][17];

  const int bx = blockIdx.x;
  const int xcd = bx & 7, slot = bx >> 3;
  const int b = xcd >> 1;
  const int m0 = (((xcd & 1) << 6) | slot) * 32;
  const int tid = threadIdx.x;
  const int w = tid >> 6;
  const int l = tid & 63;
  const int lr = l & 15, lg = l >> 4;

  const f16* Qb = Qtb + (size_t)b * 256 * 1024;
  const f16* Vb = V4 + (size_t)b * 256 * 1024;
  const float* Zb = Zinv + b * NN;

  half8 bq[2][2];
  LOADQ((m0 >> 4), bq[0][0], bq[0][1]);
  LOADQ((m0 >> 4) + 1, bq[1][0], bq[1][1]);

  floatx4 o[4][2];
#pragma unroll
  for (int cs = 0; cs < 4; ++cs)
#pragma unroll
    for (int t = 0; t < 2; ++t) o[cs][t] = (floatx4){0.f, 0.f, 0.f, 0.f};

#pragma unroll 2
  for (int it = 0; it < 32; ++it) {
    const int T = it * 8 + w;
    half8 a0, a1;
    LOADQ(T, a0, a1);
    half4 va[4];
    LOADV(T, va);
    const float4 zi = *(const float4*)(Zb + T * 16 + 4 * lg);

    floatx4 dA = {-SHIFT2, -SHIFT2, -SHIFT2, -SHIFT2};
    floatx4 dB = {-SHIFT2, -SHIFT2, -SHIFT2, -SHIFT2};
    dA = __builtin_amdgcn_mfma_f32_16x16x32_f16(a0, bq[0][0], dA, 0, 0, 0);
    dB = __builtin_amdgcn_mfma_f32_16x16x32_f16(a0, bq[1][0], dB, 0, 0, 0);
    dA = __builtin_amdgcn_mfma_f32_16x16x32_f16(a1, bq[0][1], dA, 0, 0, 0);
    dB = __builtin_amdgcn_mfma_f32_16x16x32_f16(a1, bq[1][1], dB, 0, 0, 0);

    half2v p0a = pkrtz(__builtin_amdgcn_exp2f(dA[0]) * zi.x,
                       __builtin_amdgcn_exp2f(dA[1]) * zi.y);
    half2v p0b = pkrtz(__builtin_amdgcn_exp2f(dA[2]) * zi.z,
                       __builtin_amdgcn_exp2f(dA[3]) * zi.w);
    half2v p1a = pkrtz(__builtin_amdgcn_exp2f(dB[0]) * zi.x,
                       __builtin_amdgcn_exp2f(dB[1]) * zi.y);
    half2v p1b = pkrtz(__builtin_amdgcn_exp2f(dB[2]) * zi.z,
                       __builtin_amdgcn_exp2f(dB[3]) * zi.w);
    half4 bt0 = {p0a[0], p0a[1], p0b[0], p0b[1]};
    half4 bt1 = {p1a[0], p1a[1], p1b[0], p1b[1]};
#pragma unroll
    for (int cs = 0; cs < 4; ++cs) {
      o[cs][0] = __builtin_amdgcn_mfma_f32_16x16x16f16(va[cs], bt0, o[cs][0], 0, 0, 0);
      o[cs][1] = __builtin_amdgcn_mfma_f32_16x16x16f16(va[cs], bt1, o[cs][1], 0, 0, 0);
    }
  }

#pragma unroll 1
  for (int cs = 0; cs < 4; ++cs) {
    __syncthreads();
#pragma unroll
    for (int t = 0; t < 2; ++t)
#pragma unroll
      for (int i = 0; i < 4; ++i)
        red[w][t][4 * lg + i][lr] = o[cs][t][i];
    __syncthreads();
    const int t = tid >> 8;
    const int r = (tid >> 4) & 15;
    const int col = tid & 15;
    float ssum = 0.f;
#pragma unroll
    for (int ww = 0; ww < 8; ++ww) ssum += red[ww][t][r][col];
    Out[((size_t)b * C4C + cs * 16 + r) * NN + m0 + t * 16 + col] = ssum;
  }
}

// ---------------- launch ----------------
// ws layout (4.06 MiB, no aliasing):
//   Qtb  f16 [4][256][2][64][8] 2 MiB    @ 0        (frag-blocked Q)
//   V4   f16 [4][256][64][16]   2 MiB    @ 2 MiB    (blocked V, PV A-frag)
//   Zinv f32 [4][4096]          64 KiB   @ 4 MiB
extern "C" void kernel_launch(void* const* d_in, const int* in_sizes, int n_in,
                              void* d_out, int out_size, void* d_ws, size_t ws_size,
                              hipStream_t stream)
{
  const float* x   = (const float*)d_in[0];
  const float* Wqk = (const float*)d_in[1];
  const float* Wv  = (const float*)d_in[2];
  const float* bv  = (const float*)d_in[3];
  float* out = (float*)d_out;

  char* ws = (char*)d_ws;
  f16*   Qtb  = (f16*)(ws);
  f16*   V4   = (f16*)(ws + (2u << 20));
  float* Zinv = (float*)(ws + (4u << 20));

  void* args[] = {(void*)&x, (void*)&Wqk, (void*)&Wv, (void*)&bv,
                  (void*)&Qtb, (void*)&V4, (void*)&Zinv, (void*)&out};
  hipError_t rc = hipLaunchCooperativeKernel((const void*)fused_kernel,
                                             dim3(512), dim3(512),
                                             args, 0, stream);
  if (rc != hipSuccess) {
    // fallback: R24's three dispatches (measured 60.5 us)
    qv_kernel<<<dim3(128, 4), 256, 0, stream>>>(x, Wqk, Wv, bv, Qtb, V4);
    z_kernel<<<dim3(256), 512, 0, stream>>>(Qtb, Zinv);
    av_kernel<<<dim3(512), 512, 0, stream>>>(Qtb, V4, Zinv, out);
  }
}

// Round 26
// 60.490 us; speedup vs baseline: 3.2942x; 3.2942x over previous
//
#include <hip/hip_runtime.h>

// Problem: B=4, C=256, C4=64, N=4096, f32 in/out.
//   Q = Wqk@x; V = Wv@x + b; E = Q^T Q / 8; A = softmax_rows(E); out = V @ A
// Fused: out[c,m] = sum_n V[c,n] * exp2(dot_nm - 12) * Zinv[n],
//        Zinv[n] = 4096 / sum_m exp2(dot_nm);  dot = log2e*E (Qt pre-scaled).
// R14: FRAG-BLOCKED Qt — contiguous 1-KB wave tile loads (the big unlock).
// R20: no u_kernel; V blocked f16; precomputed Zinv folded into av's bt.
// R23/R24: z = 64-n x full-m blocks writing Zinv directly; 3 dispatches.
// R26: exact R24 restore (measured best 60.5 us). R25's cooperative fusion
// spilled (WRITE 111 MB scratch, 199 us) — separate dispatches preserve the
// per-kernel register balance and are load-bearing, not overhead.

#define CC 256
#define C4C 64
#define NBATCH 4
#define NN 4096
#define QSCALE 0.42466089f   // sqrt(log2(e)/8)
#define SHIFT2 12.0f

typedef _Float16 f16;
typedef _Float16 half2v __attribute__((ext_vector_type(2)));
typedef _Float16 half4 __attribute__((ext_vector_type(4)));
typedef _Float16 half8 __attribute__((ext_vector_type(8)));
typedef __fp16 fp16x2 __attribute__((ext_vector_type(2)));
typedef float floatx4 __attribute__((ext_vector_type(4)));

static __device__ __forceinline__ half2v pkrtz(float a, float b) {
  fp16x2 r = __builtin_amdgcn_cvt_pkrtz(a, b);
  return __builtin_bit_cast(half2v, r);
}

// Load one 16-n tile's MFMA frag pair: lane l gets {row=l&15, k=8*(l>>4)+j}
#define LOADQ(T, A0, A1)                                                   \
  { const f16* p_ = Qb + (size_t)(T) * 1024 + l * 8;                       \
    A0 = *(const half8*)(p_); A1 = *(const half8*)(p_ + 512); }

// ---------------- QV: Q/V projections via MFMA -------------------------------
// grid (128, 4) block 256 (4 waves). Block tile: 128 oc x 32 n, K=C=256.
// Q -> frag-blocked Qtb; V -> blocked f16 V4[b][T][c][16] (PV A-frag layout).
#define XT_PITCH 264
__global__ __launch_bounds__(256) void qv_kernel(
    const float* __restrict__ x, const float* __restrict__ Wqk,
    const float* __restrict__ Wv, const float* __restrict__ bv,
    f16* __restrict__ Qtb, f16* __restrict__ V4)
{
  __shared__ __align__(16) f16 xt[32][XT_PITCH];
  const int b = blockIdx.y;
  const int n0 = blockIdx.x * 32;
  const int tid = threadIdx.x;

  {
    const int nq = tid & 7;
    const int cb = tid >> 3;
    const int c = cb * 8;
    const float* xp = x + (size_t)b * CC * NN + n0 + nq * 4;
    float4 r[8];
#pragma unroll
    for (int j = 0; j < 8; ++j)
      r[j] = *(const float4*)(xp + (size_t)(c + j) * NN);
#pragma unroll
    for (int s = 0; s < 4; ++s) {
      half8 h;
#pragma unroll
      for (int j = 0; j < 8; ++j) h[j] = (f16)(((const float*)&r[j])[s]);
      *(half8*)(&xt[nq * 4 + s][c]) = h;
    }
  }

  const int w = tid >> 6, l = tid & 63, lr = l & 15, lg = l >> 4;
  const float* Wsrc = (w < 2) ? Wqk : Wv;
  const int ocb = (w & 1) * 32;
  half8 af[2][8];
#pragma unroll
  for (int t = 0; t < 2; ++t) {
    const float* wp = Wsrc + (size_t)(ocb + t * 16 + lr) * CC + 8 * lg;
#pragma unroll
    for (int kk = 0; kk < 8; ++kk) {
      float4 wa = *(const float4*)(wp + kk * 32);
      float4 wb = *(const float4*)(wp + kk * 32 + 4);
      half8 h;
      h[0] = (f16)wa.x; h[1] = (f16)wa.y; h[2] = (f16)wa.z; h[3] = (f16)wa.w;
      h[4] = (f16)wb.x; h[5] = (f16)wb.y; h[6] = (f16)wb.z; h[7] = (f16)wb.w;
      af[t][kk] = h;
    }
  }

  __syncthreads();

  floatx4 acc[2][2] = {{{0.f,0.f,0.f,0.f},{0.f,0.f,0.f,0.f}},
                       {{0.f,0.f,0.f,0.f},{0.f,0.f,0.f,0.f}}};
#pragma unroll
  for (int nt = 0; nt < 2; ++nt) {
#pragma unroll
    for (int kk = 0; kk < 8; ++kk) {
      half8 bf = *(const half8*)(&xt[nt * 16 + lr][kk * 32 + 8 * lg]);
      acc[0][nt] = __builtin_amdgcn_mfma_f32_16x16x32_f16(af[0][kk], bf, acc[0][nt], 0, 0, 0);
      acc[1][nt] = __builtin_amdgcn_mfma_f32_16x16x32_f16(af[1][kk], bf, acc[1][nt], 0, 0, 0);
    }
  }

  if (w < 2) {
    // Q blocked write: oc = w*32+t*16+4lg+i -> kg=2t+(lg>>1)
#pragma unroll
    for (int t = 0; t < 2; ++t)
#pragma unroll
      for (int nt = 0; nt < 2; ++nt) {
        int T = (n0 >> 4) + nt;
        int kg = 2 * t + (lg >> 1);
        union { f16 h[4]; unsigned long long u; } q4;
#pragma unroll
        for (int i = 0; i < 4; ++i) q4.h[i] = (f16)(acc[t][nt][i] * QSCALE);
        *(unsigned long long*)(Qtb + (size_t)(b * 256 + T) * 1024 + w * 512
                               + (kg * 16 + lr) * 8 + (lg & 1) * 4) = q4.u;
      }
  } else {
    // V blocked f16 write: idx = (b*256+T)*1024 + oc*16 + lr
#pragma unroll
    for (int t = 0; t < 2; ++t)
#pragma unroll
      for (int nt = 0; nt < 2; ++nt) {
        int T = (n0 >> 4) + nt;
        int oc = (w - 2) * 32 + t * 16 + 4 * lg;
#pragma unroll
        for (int i = 0; i < 4; ++i)
          V4[(size_t)(b * 256 + T) * 1024 + (oc + i) * 16 + lr] =
              (f16)(acc[t][nt][i] + bv[oc + i]);
      }
  }
}

// ---------------- Z pass: 64-n x full-m blocks, 8 waves, Zinv direct ---------
// grid 256 (XCD-swizzled) block 512 (8 waves). Block: 64 n (a[4][2] hoisted)
// x ALL 4096 m. Wave w streams 32 m-tiles (4 chunks of 8 preloaded), 8 MFMA
// per tile. Block reduce over 8 waves -> complete Z[n] -> Zinv = 4096/Z.
__global__ __launch_bounds__(512) void z_kernel(
    const f16* __restrict__ Qtb, float* __restrict__ Zinv)
{
  __shared__ float zl[8][64];
  const int bx = blockIdx.x;
  const int xcd = bx & 7, slot = bx >> 3;       // slot 0..31
  const int b = xcd >> 1;                        // 2 XCDs per batch
  const int wu = ((xcd & 1) << 5) | slot;        // 0..63 per batch: n-group
  const int n0t = wu * 4;                        // n-tile base (64 n)
  const int tid = threadIdx.x;
  const int w = tid >> 6, l = tid & 63, lr = l & 15, lg = l >> 4;
  const f16* Qb = Qtb + (size_t)b * 256 * 1024;

  half8 a[4][2];
#pragma unroll
  for (int t = 0; t < 4; ++t) LOADQ(n0t + t, a[t][0], a[t][1]);

  const int tstr = w * 32;                       // wave's 32-tile m strip
  float rs[4][4];
#pragma unroll
  for (int t = 0; t < 4; ++t)
#pragma unroll
    for (int i = 0; i < 4; ++i) rs[t][i] = 0.f;

#pragma unroll 1
  for (int ch = 0; ch < 4; ++ch) {
    half8 bb[8][2];
#pragma unroll
    for (int mt = 0; mt < 8; ++mt) {
      const f16* p_ = Qb + (size_t)(tstr + ch * 8 + mt) * 1024 + l * 8;
      bb[mt][0] = *(const half8*)(p_);
      bb[mt][1] = *(const half8*)(p_ + 512);
    }
#pragma unroll
    for (int mt = 0; mt < 8; ++mt) {
      floatx4 d[4];
#pragma unroll
      for (int t = 0; t < 4; ++t) {
        d[t] = (floatx4){0.f, 0.f, 0.f, 0.f};
        d[t] = __builtin_amdgcn_mfma_f32_16x16x32_f16(a[t][0], bb[mt][0], d[t], 0, 0, 0);
        d[t] = __builtin_amdgcn_mfma_f32_16x16x32_f16(a[t][1], bb[mt][1], d[t], 0, 0, 0);
      }
#pragma unroll
      for (int t = 0; t < 4; ++t)
#pragma unroll
        for (int i = 0; i < 4; ++i)
          rs[t][i] += __builtin_amdgcn_exp2f(d[t][i]);
    }
  }

#pragma unroll
  for (int t = 0; t < 4; ++t)
#pragma unroll
    for (int i = 0; i < 4; ++i) {
      float v = rs[t][i];
      v += __shfl_xor(v, 1); v += __shfl_xor(v, 2);
      v += __shfl_xor(v, 4); v += __shfl_xor(v, 8);
      rs[t][i] = v;
    }
  if (lr == 0) {
#pragma unroll
    for (int t = 0; t < 4; ++t)
#pragma unroll
      for (int i = 0; i < 4; ++i)
        zl[w][16 * t + 4 * lg + i] = rs[t][i];
  }
  __syncthreads();
  if (tid < 64) {   // fixed-order 8-wave sum -> complete Z -> Zinv
    float s = 0.f;
#pragma unroll
    for (int ww = 0; ww < 8; ++ww) s += zl[ww][tid];
    Zinv[b * NN + n0t * 16 + tid] = 4096.0f / s;
  }
}

// ---------------- PV pass (R20 exact): blocked loads, zi fold, unroll 2 ------
#define LOADV(NB, UA)                                                      \
  { const f16* up_ = Vb + (size_t)(NB) * 1024 + 4 * lg;                    \
    _Pragma("unroll")                                                      \
    for (int cs = 0; cs < 4; ++cs)                                         \
      UA[cs] = *(const half4*)(up_ + (16 * cs + lr) * 16); }

__global__ __launch_bounds__(512, 4) void av_kernel(
    const f16* __restrict__ Qtb, const f16* __restrict__ V4,
    const float* __restrict__ Zinv, float* __restrict__ Out)
{
  __shared__ float red[8][2][16][17];  // ~17.4 KB

  const int bx = blockIdx.x;
  const int xcd = bx & 7, slot = bx >> 3;          // slot 0..63
  const int b = xcd >> 1;                          // 2 XCDs per batch
  const int m0 = (((xcd & 1) << 6) | slot) * 32;   // 128 m-tiles per batch
  const int tid = threadIdx.x;
  const int w = tid >> 6;                          // 0..7
  const int l = tid & 63;
  const int lr = l & 15, lg = l >> 4;

  const f16* Qb = Qtb + (size_t)b * 256 * 1024;
  const f16* Vb = V4 + (size_t)b * 256 * 1024;
  const float* Zb = Zinv + b * NN;

  half8 bq[2][2];
  LOADQ((m0 >> 4), bq[0][0], bq[0][1]);
  LOADQ((m0 >> 4) + 1, bq[1][0], bq[1][1]);

  floatx4 o[4][2];
#pragma unroll
  for (int cs = 0; cs < 4; ++cs)
#pragma unroll
    for (int t = 0; t < 2; ++t) o[cs][t] = (floatx4){0.f, 0.f, 0.f, 0.f};

#pragma unroll 2
  for (int it = 0; it < 32; ++it) {
    const int T = it * 8 + w;                      // this wave's n-tile
    half8 a0, a1;
    LOADQ(T, a0, a1);
    half4 va[4];
    LOADV(T, va);
    const float4 zi = *(const float4*)(Zb + T * 16 + 4 * lg);

    floatx4 dA = {-SHIFT2, -SHIFT2, -SHIFT2, -SHIFT2};
    floatx4 dB = {-SHIFT2, -SHIFT2, -SHIFT2, -SHIFT2};
    dA = __builtin_amdgcn_mfma_f32_16x16x32_f16(a0, bq[0][0], dA, 0, 0, 0);
    dB = __builtin_amdgcn_mfma_f32_16x16x32_f16(a0, bq[1][0], dB, 0, 0, 0);
    dA = __builtin_amdgcn_mfma_f32_16x16x32_f16(a1, bq[0][1], dA, 0, 0, 0);
    dB = __builtin_amdgcn_mfma_f32_16x16x32_f16(a1, bq[1][1], dB, 0, 0, 0);

    half2v p0a = pkrtz(__builtin_amdgcn_exp2f(dA[0]) * zi.x,
                       __builtin_amdgcn_exp2f(dA[1]) * zi.y);
    half2v p0b = pkrtz(__builtin_amdgcn_exp2f(dA[2]) * zi.z,
                       __builtin_amdgcn_exp2f(dA[3]) * zi.w);
    half2v p1a = pkrtz(__builtin_amdgcn_exp2f(dB[0]) * zi.x,
                       __builtin_amdgcn_exp2f(dB[1]) * zi.y);
    half2v p1b = pkrtz(__builtin_amdgcn_exp2f(dB[2]) * zi.z,
                       __builtin_amdgcn_exp2f(dB[3]) * zi.w);
    half4 bt0 = {p0a[0], p0a[1], p0b[0], p0b[1]};
    half4 bt1 = {p1a[0], p1a[1], p1b[0], p1b[1]};
#pragma unroll
    for (int cs = 0; cs < 4; ++cs) {
      o[cs][0] = __builtin_amdgcn_mfma_f32_16x16x16f16(va[cs], bt0, o[cs][0], 0, 0, 0);
      o[cs][1] = __builtin_amdgcn_mfma_f32_16x16x16f16(va[cs], bt1, o[cs][1], 0, 0, 0);
    }
  }

  // ---- 8-wave reduction, fixed order: deterministic, direct stores ----
#pragma unroll 1
  for (int cs = 0; cs < 4; ++cs) {
    __syncthreads();
#pragma unroll
    for (int t = 0; t < 2; ++t)
#pragma unroll
      for (int i = 0; i < 4; ++i)
        red[w][t][4 * lg + i][lr] = o[cs][t][i];
    __syncthreads();
    const int t = tid >> 8;              // 0..1
    const int r = (tid >> 4) & 15;       // 0..15
    const int col = tid & 15;            // 0..15
    float ssum = 0.f;
#pragma unroll
    for (int ww = 0; ww < 8; ++ww) ssum += red[ww][t][r][col];
    Out[((size_t)b * C4C + cs * 16 + r) * NN + m0 + t * 16 + col] = ssum;
  }
}

// ---------------- launch ----------------
// ws layout (4.06 MiB, no aliasing):
//   Qtb  f16 [4][256][2][64][8] 2 MiB    @ 0        (frag-blocked Q)
//   V4   f16 [4][256][64][16]   2 MiB    @ 2 MiB    (blocked V, PV A-frag)
//   Zinv f32 [4][4096]          64 KiB   @ 4 MiB
extern "C" void kernel_launch(void* const* d_in, const int* in_sizes, int n_in,
                              void* d_out, int out_size, void* d_ws, size_t ws_size,
                              hipStream_t stream)
{
  const float* x   = (const float*)d_in[0];
  const float* Wqk = (const float*)d_in[1];
  const float* Wv  = (const float*)d_in[2];
  const float* bv  = (const float*)d_in[3];
  float* out = (float*)d_out;

  char* ws = (char*)d_ws;
  f16*   Qtb  = (f16*)(ws);
  f16*   V4   = (f16*)(ws + (2u << 20));
  float* Zinv = (float*)(ws + (4u << 20));

  qv_kernel<<<dim3(128, 4), 256, 0, stream>>>(x, Wqk, Wv, bv, Qtb, V4);
  z_kernel<<<dim3(256), 512, 0, stream>>>(Qtb, Zinv);
  av_kernel<<<dim3(512), 512, 0, stream>>>(Qtb, V4, Zinv, out);
}

// Round 27
// 58.148 us; speedup vs baseline: 3.4268x; 1.0403x over previous
//
#include <hip/hip_runtime.h>

// Problem: B=4, C=256, C4=64, N=4096, f32 in/out.
//   Q = Wqk@x; V = Wv@x + b; E = Q^T Q / 8; A = softmax_rows(E); out = V @ A
// Fused: out[c,m] = sum_n U[c,n] * exp2(dot_nm - 12),
//        U = V * 4096/Z (scaled IN z's epilogue), Z[n] = sum_m exp2(dot_nm).
// R14: FRAG-BLOCKED Qt — contiguous 1-KB wave tile loads (the big unlock).
// R23/R24: z = 64-n x full-m blocks; 3 dispatches (R25 fusion spilled: revert).
// R27: zi-scaling moved OUT of av's hot loop (R22 showed av is hypersensitive
// to per-iter loads): z's epilogue scales its 64-n slice of V4 in place
// (single writer, deterministic). av: bt = pkrtz(exp2(d)) — no zi load/muls.

#define CC 256
#define C4C 64
#define NBATCH 4
#define NN 4096
#define QSCALE 0.42466089f   // sqrt(log2(e)/8)
#define SHIFT2 12.0f

typedef _Float16 f16;
typedef _Float16 half2v __attribute__((ext_vector_type(2)));
typedef _Float16 half4 __attribute__((ext_vector_type(4)));
typedef _Float16 half8 __attribute__((ext_vector_type(8)));
typedef __fp16 fp16x2 __attribute__((ext_vector_type(2)));
typedef float floatx4 __attribute__((ext_vector_type(4)));

static __device__ __forceinline__ half2v pkrtz(float a, float b) {
  fp16x2 r = __builtin_amdgcn_cvt_pkrtz(a, b);
  return __builtin_bit_cast(half2v, r);
}

// Load one 16-n tile's MFMA frag pair: lane l gets {row=l&15, k=8*(l>>4)+j}
#define LOADQ(T, A0, A1)                                                   \
  { const f16* p_ = Qb + (size_t)(T) * 1024 + l * 8;                       \
    A0 = *(const half8*)(p_); A1 = *(const half8*)(p_ + 512); }

// ---------------- QV: Q/V projections via MFMA -------------------------------
// grid (128, 4) block 256 (4 waves). Block tile: 128 oc x 32 n, K=C=256.
// Q -> frag-blocked Qtb; V -> blocked f16 V4[b][T][c][16] (PV A-frag layout).
#define XT_PITCH 264
__global__ __launch_bounds__(256) void qv_kernel(
    const float* __restrict__ x, const float* __restrict__ Wqk,
    const float* __restrict__ Wv, const float* __restrict__ bv,
    f16* __restrict__ Qtb, f16* __restrict__ V4)
{
  __shared__ __align__(16) f16 xt[32][XT_PITCH];
  const int b = blockIdx.y;
  const int n0 = blockIdx.x * 32;
  const int tid = threadIdx.x;

  {
    const int nq = tid & 7;
    const int cb = tid >> 3;
    const int c = cb * 8;
    const float* xp = x + (size_t)b * CC * NN + n0 + nq * 4;
    float4 r[8];
#pragma unroll
    for (int j = 0; j < 8; ++j)
      r[j] = *(const float4*)(xp + (size_t)(c + j) * NN);
#pragma unroll
    for (int s = 0; s < 4; ++s) {
      half8 h;
#pragma unroll
      for (int j = 0; j < 8; ++j) h[j] = (f16)(((const float*)&r[j])[s]);
      *(half8*)(&xt[nq * 4 + s][c]) = h;
    }
  }

  const int w = tid >> 6, l = tid & 63, lr = l & 15, lg = l >> 4;
  const float* Wsrc = (w < 2) ? Wqk : Wv;
  const int ocb = (w & 1) * 32;
  half8 af[2][8];
#pragma unroll
  for (int t = 0; t < 2; ++t) {
    const float* wp = Wsrc + (size_t)(ocb + t * 16 + lr) * CC + 8 * lg;
#pragma unroll
    for (int kk = 0; kk < 8; ++kk) {
      float4 wa = *(const float4*)(wp + kk * 32);
      float4 wb = *(const float4*)(wp + kk * 32 + 4);
      half8 h;
      h[0] = (f16)wa.x; h[1] = (f16)wa.y; h[2] = (f16)wa.z; h[3] = (f16)wa.w;
      h[4] = (f16)wb.x; h[5] = (f16)wb.y; h[6] = (f16)wb.z; h[7] = (f16)wb.w;
      af[t][kk] = h;
    }
  }

  __syncthreads();

  floatx4 acc[2][2] = {{{0.f,0.f,0.f,0.f},{0.f,0.f,0.f,0.f}},
                       {{0.f,0.f,0.f,0.f},{0.f,0.f,0.f,0.f}}};
#pragma unroll
  for (int nt = 0; nt < 2; ++nt) {
#pragma unroll
    for (int kk = 0; kk < 8; ++kk) {
      half8 bf = *(const half8*)(&xt[nt * 16 + lr][kk * 32 + 8 * lg]);
      acc[0][nt] = __builtin_amdgcn_mfma_f32_16x16x32_f16(af[0][kk], bf, acc[0][nt], 0, 0, 0);
      acc[1][nt] = __builtin_amdgcn_mfma_f32_16x16x32_f16(af[1][kk], bf, acc[1][nt], 0, 0, 0);
    }
  }

  if (w < 2) {
    // Q blocked write: oc = w*32+t*16+4lg+i -> kg=2t+(lg>>1)
#pragma unroll
    for (int t = 0; t < 2; ++t)
#pragma unroll
      for (int nt = 0; nt < 2; ++nt) {
        int T = (n0 >> 4) + nt;
        int kg = 2 * t + (lg >> 1);
        union { f16 h[4]; unsigned long long u; } q4;
#pragma unroll
        for (int i = 0; i < 4; ++i) q4.h[i] = (f16)(acc[t][nt][i] * QSCALE);
        *(unsigned long long*)(Qtb + (size_t)(b * 256 + T) * 1024 + w * 512
                               + (kg * 16 + lr) * 8 + (lg & 1) * 4) = q4.u;
      }
  } else {
    // V blocked f16 write: idx = (b*256+T)*1024 + oc*16 + lr
#pragma unroll
    for (int t = 0; t < 2; ++t)
#pragma unroll
      for (int nt = 0; nt < 2; ++nt) {
        int T = (n0 >> 4) + nt;
        int oc = (w - 2) * 32 + t * 16 + 4 * lg;
#pragma unroll
        for (int i = 0; i < 4; ++i)
          V4[(size_t)(b * 256 + T) * 1024 + (oc + i) * 16 + lr] =
              (f16)(acc[t][nt][i] + bv[oc + i]);
      }
  }
}

// ---------------- Z pass: 64-n x full-m blocks + in-place V4 scaling ---------
// grid 256 (XCD-swizzled) block 512 (8 waves). Block: 64 n (a[4][2] hoisted)
// x ALL 4096 m. Wave w streams 32 m-tiles (4 chunks of 8 preloaded), 8 MFMA
// per tile. Block reduce -> complete Z[n] -> zi = 4096/Z stored in LDS ->
// epilogue scales the block's 64-n slice of V4 in place (U = V*zi, single
// writer per element -> deterministic). av needs no zi at all.
__global__ __launch_bounds__(512) void z_kernel(
    const f16* __restrict__ Qtb, f16* __restrict__ V4)
{
  __shared__ float zl[8][64];
  __shared__ float ziس[64];
  const int bx = blockIdx.x;
  const int xcd = bx & 7, slot = bx >> 3;       // slot 0..31
  const int b = xcd >> 1;                        // 2 XCDs per batch
  const int wu = ((xcd & 1) << 5) | slot;        // 0..63 per batch: n-group
  const int n0t = wu * 4;                        // n-tile base (64 n)
  const int tid = threadIdx.x;
  const int w = tid >> 6, l = tid & 63, lr = l & 15, lg = l >> 4;
  const f16* Qb = Qtb + (size_t)b * 256 * 1024;

  half8 a[4][2];
#pragma unroll
  for (int t = 0; t < 4; ++t) LOADQ(n0t + t, a[t][0], a[t][1]);

  const int tstr = w * 32;                       // wave's 32-tile m strip
  float rs[4][4];
#pragma unroll
  for (int t = 0; t < 4; ++t)
#pragma unroll
    for (int i = 0; i < 4; ++i) rs[t][i] = 0.f;

#pragma unroll 1
  for (int ch = 0; ch < 4; ++ch) {
    half8 bb[8][2];
#pragma unroll
    for (int mt = 0; mt < 8; ++mt) {
      const f16* p_ = Qb + (size_t)(tstr + ch * 8 + mt) * 1024 + l * 8;
      bb[mt][0] = *(const half8*)(p_);
      bb[mt][1] = *(const half8*)(p_ + 512);
    }
#pragma unroll
    for (int mt = 0; mt < 8; ++mt) {
      floatx4 d[4];
#pragma unroll
      for (int t = 0; t < 4; ++t) {
        d[t] = (floatx4){0.f, 0.f, 0.f, 0.f};
        d[t] = __builtin_amdgcn_mfma_f32_16x16x32_f16(a[t][0], bb[mt][0], d[t], 0, 0, 0);
        d[t] = __builtin_amdgcn_mfma_f32_16x16x32_f16(a[t][1], bb[mt][1], d[t], 0, 0, 0);
      }
#pragma unroll
      for (int t = 0; t < 4; ++t)
#pragma unroll
        for (int i = 0; i < 4; ++i)
          rs[t][i] += __builtin_amdgcn_exp2f(d[t][i]);
    }
  }

#pragma unroll
  for (int t = 0; t < 4; ++t)
#pragma unroll
    for (int i = 0; i < 4; ++i) {
      float v = rs[t][i];
      v += __shfl_xor(v, 1); v += __shfl_xor(v, 2);
      v += __shfl_xor(v, 4); v += __shfl_xor(v, 8);
      rs[t][i] = v;
    }
  if (lr == 0) {
#pragma unroll
    for (int t = 0; t < 4; ++t)
#pragma unroll
      for (int i = 0; i < 4; ++i)
        zl[w][16 * t + 4 * lg + i] = rs[t][i];
  }
  __syncthreads();
  if (tid < 64) {   // fixed-order 8-wave sum -> complete Z -> zi
    float s = 0.f;
#pragma unroll
    for (int ww = 0; ww < 8; ++ww) s += zl[ww][tid];
    ziس[tid] = 4096.0f / s;
  }
  __syncthreads();
  // ---- epilogue: U = V * zi for this block's 64-n slice (8 KB), in place ----
  {
    f16* vp = V4 + (size_t)(b * 256 + n0t) * 1024;   // 4 tiles = 4096 f16
    const int e0 = tid * 8;                           // 512 thr x 8 f16
    const int nloc = ((e0 >> 10) << 4) | (e0 & 15);   // tile*16 + (n&15); 8 elems span n..n+7? no:
    // layout [T][c][16]: 8 consecutive f16 = {c fixed, n-within-16 = 8h..8h+8}
    half8 v = *(const half8*)(vp + e0);
    const int T_rel = e0 >> 10;                       // 0..3
    const int nw = e0 & 15;                           // 0 or 8 (e0 % 16 with 8-stride)
    half8 u;
#pragma unroll
    for (int j = 0; j < 8; ++j) {
      float zi = ziس[T_rel * 16 + nw + j];
      u[j] = (f16)((float)v[j] * zi);
    }
    *(half8*)(vp + e0) = u;
  }
}

// ---------------- PV pass: blocked loads, NO zi in loop, unroll 2 ------------
// grid 512 (XCD-swizzled) block 512 (8 waves, (512,4)). Block: 32 m, all n.
// Wave w: tiles w+8i, i=0..31. Per step: LOADQ + LOADV ->
//   E-MFMA x4 (C=-12) -> exp2 -> pkrtz -> PV-MFMA x8 (K=16).
// End: fixed-order 8-wave LDS reduction (deterministic), direct stores.
#define LOADV(NB, UA)                                                      \
  { const f16* up_ = Vb + (size_t)(NB) * 1024 + 4 * lg;                    \
    _Pragma("unroll")                                                      \
    for (int cs = 0; cs < 4; ++cs)                                         \
      UA[cs] = *(const half4*)(up_ + (16 * cs + lr) * 16); }

__global__ __launch_bounds__(512, 4) void av_kernel(
    const f16* __restrict__ Qtb, const f16* __restrict__ V4,
    float* __restrict__ Out)
{
  __shared__ float red[8][2][16][17];  // ~17.4 KB

  const int bx = blockIdx.x;
  const int xcd = bx & 7, slot = bx >> 3;          // slot 0..63
  const int b = xcd >> 1;                          // 2 XCDs per batch
  const int m0 = (((xcd & 1) << 6) | slot) * 32;   // 128 m-tiles per batch
  const int tid = threadIdx.x;
  const int w = tid >> 6;                          // 0..7
  const int l = tid & 63;
  const int lr = l & 15, lg = l >> 4;

  const f16* Qb = Qtb + (size_t)b * 256 * 1024;
  const f16* Vb = V4 + (size_t)b * 256 * 1024;

  half8 bq[2][2];
  LOADQ((m0 >> 4), bq[0][0], bq[0][1]);
  LOADQ((m0 >> 4) + 1, bq[1][0], bq[1][1]);

  floatx4 o[4][2];
#pragma unroll
  for (int cs = 0; cs < 4; ++cs)
#pragma unroll
    for (int t = 0; t < 2; ++t) o[cs][t] = (floatx4){0.f, 0.f, 0.f, 0.f};

#pragma unroll 2
  for (int it = 0; it < 32; ++it) {
    const int T = it * 8 + w;                      // this wave's n-tile
    half8 a0, a1;
    LOADQ(T, a0, a1);
    half4 va[4];
    LOADV(T, va);

    floatx4 dA = {-SHIFT2, -SHIFT2, -SHIFT2, -SHIFT2};
    floatx4 dB = {-SHIFT2, -SHIFT2, -SHIFT2, -SHIFT2};
    dA = __builtin_amdgcn_mfma_f32_16x16x32_f16(a0, bq[0][0], dA, 0, 0, 0);
    dB = __builtin_amdgcn_mfma_f32_16x16x32_f16(a0, bq[1][0], dB, 0, 0, 0);
    dA = __builtin_amdgcn_mfma_f32_16x16x32_f16(a1, bq[0][1], dA, 0, 0, 0);
    dB = __builtin_amdgcn_mfma_f32_16x16x32_f16(a1, bq[1][1], dB, 0, 0, 0);

    half2v p0a = pkrtz(__builtin_amdgcn_exp2f(dA[0]), __builtin_amdgcn_exp2f(dA[1]));
    half2v p0b = pkrtz(__builtin_amdgcn_exp2f(dA[2]), __builtin_amdgcn_exp2f(dA[3]));
    half2v p1a = pkrtz(__builtin_amdgcn_exp2f(dB[0]), __builtin_amdgcn_exp2f(dB[1]));
    half2v p1b = pkrtz(__builtin_amdgcn_exp2f(dB[2]), __builtin_amdgcn_exp2f(dB[3]));
    half4 bt0 = {p0a[0], p0a[1], p0b[0], p0b[1]};
    half4 bt1 = {p1a[0], p1a[1], p1b[0], p1b[1]};
#pragma unroll
    for (int cs = 0; cs < 4; ++cs) {
      o[cs][0] = __builtin_amdgcn_mfma_f32_16x16x16f16(va[cs], bt0, o[cs][0], 0, 0, 0);
      o[cs][1] = __builtin_amdgcn_mfma_f32_16x16x16f16(va[cs], bt1, o[cs][1], 0, 0, 0);
    }
  }

  // ---- 8-wave reduction, fixed order: deterministic, direct stores ----
#pragma unroll 1
  for (int cs = 0; cs < 4; ++cs) {
    __syncthreads();
#pragma unroll
    for (int t = 0; t < 2; ++t)
#pragma unroll
      for (int i = 0; i < 4; ++i)
        red[w][t][4 * lg + i][lr] = o[cs][t][i];
    __syncthreads();
    const int t = tid >> 8;              // 0..1
    const int r = (tid >> 4) & 15;       // 0..15
    const int col = tid & 15;            // 0..15
    float ssum = 0.f;
#pragma unroll
    for (int ww = 0; ww < 8; ++ww) ssum += red[ww][t][r][col];
    Out[((size_t)b * C4C + cs * 16 + r) * NN + m0 + t * 16 + col] = ssum;
  }
}

// ---------------- launch ----------------
// ws layout (4 MiB, no aliasing):
//   Qtb  f16 [4][256][2][64][8] 2 MiB    @ 0        (frag-blocked Q)
//   V4   f16 [4][256][64][16]   2 MiB    @ 2 MiB    (blocked V; z scales->U)
extern "C" void kernel_launch(void* const* d_in, const int* in_sizes, int n_in,
                              void* d_out, int out_size, void* d_ws, size_t ws_size,
                              hipStream_t stream)
{
  const float* x   = (const float*)d_in[0];
  const float* Wqk = (const float*)d_in[1];
  const float* Wv  = (const float*)d_in[2];
  const float* bv  = (const float*)d_in[3];
  float* out = (float*)d_out;

  char* ws = (char*)d_ws;
  f16*   Qtb = (f16*)(ws);
  f16*   V4  = (f16*)(ws + (2u << 20));

  qv_kernel<<<dim3(128, 4), 256, 0, stream>>>(x, Wqk, Wv, bv, Qtb, V4);
  z_kernel<<<dim3(256), 512, 0, stream>>>(Qtb, V4);
  av_kernel<<<dim3(512), 512, 0, stream>>>(Qtb, V4, out);
}